// Round 1
// baseline (269.554 us; speedup 1.0000x reference)
//
#include <hip/hip_runtime.h>
#include <math.h>

// ---------------- types / helpers ----------------
typedef short s16x8 __attribute__((ext_vector_type(8)));     // 8 bf16 in 4 VGPRs
typedef unsigned short u16;
typedef unsigned short u16x4 __attribute__((ext_vector_type(4)));
typedef float f32x4 __attribute__((ext_vector_type(4)));

__device__ __forceinline__ f32x4 mfma16(s16x8 a, s16x8 b, f32x4 c) {
  return __builtin_amdgcn_mfma_f32_16x16x32_bf16(a, b, c, 0, 0, 0);
}

// fp32 -> bf16 bits, round-to-nearest-even
__device__ __forceinline__ u16 f2bf(float f) {
  unsigned u = __builtin_bit_cast(unsigned, f);
  u = (u + 0x7fffu + ((u >> 16) & 1u)) >> 16;
  return (u16)u;
}

// pack two fp32 -> two truncated bf16 in one v_perm
__device__ __forceinline__ unsigned pk_trunc(float hi, float lo) {
  return __builtin_amdgcn_perm(__builtin_bit_cast(unsigned, hi),
                               __builtin_bit_cast(unsigned, lo), 0x07060302u);
}

// async global->LDS, 16B per lane; lds base wave-uniform, lane i lands at base + i*16
__device__ __forceinline__ void gll16(const void* g, void* l) {
  __builtin_amdgcn_global_load_lds((__attribute__((address_space(1))) void*)(void*)g,
                                   (__attribute__((address_space(3))) void*)l,
                                   16, 0, 0);
}

// wave-local LDS fence: drain DS queue + compiler ordering (no workgroup barrier)
__device__ __forceinline__ void lds_fence() {
  asm volatile("s_waitcnt lgkmcnt(0)" ::: "memory");
}

// ---------------- layout/convert kernels ----------------
__global__ __launch_bounds__(256) void k_convert_x(const float* __restrict__ x,
                                                   u16* __restrict__ xb) {
  int i = (blockIdx.x * 256 + threadIdx.x) * 8;
  const float4* xv = (const float4*)(x + i);
  float4 a = xv[0], b = xv[1];
  union { s16x8 v; u16 s[8]; } r;
  r.s[0] = f2bf(a.x); r.s[1] = f2bf(a.y); r.s[2] = f2bf(a.z); r.s[3] = f2bf(a.w);
  r.s[4] = f2bf(b.x); r.s[5] = f2bf(b.y); r.s[6] = f2bf(b.z); r.s[7] = f2bf(b.w);
  *(s16x8*)(xb + i) = r.v;
}

// in: fp32 [R][C]  ->  out: bf16 [C][R]
__global__ __launch_bounds__(256) void k_transpose_w(const float* __restrict__ in,
                                                     u16* __restrict__ out, int R, int C) {
  __shared__ float tile[32][33];
  int c0 = blockIdx.x * 32, r0 = blockIdx.y * 32;
  int tx = threadIdx.x & 31, ty = threadIdx.x >> 5;  // 32 x 8
#pragma unroll
  for (int s = 0; s < 4; ++s)
    tile[ty + 8 * s][tx] = in[(size_t)(r0 + ty + 8 * s) * C + c0 + tx];
  __syncthreads();
#pragma unroll
  for (int s = 0; s < 4; ++s)
    out[(size_t)(c0 + ty + 8 * s) * R + r0 + tx] = f2bf(tile[tx][ty + 8 * s]);
}

// ---------------- GEMM: C = A[M,K] * Bt[N,K]^T + bias ----------------
// 1D grid, XCD-aware swizzle. Double-buffered LDS staging: prefetch tile kt+1
// (global_load_lds width=16) before computing on tile kt -> the barrier drain at
// loop end no longer exposes the full L2 latency. LDS 32KB; VGPR (~164) caps
// occupancy at 3 blocks/CU, so the dbuf costs no occupancy.
// EPI 0: scatter q (scaled), k as [BH][T][D]; v transposed to [BH][D][T].
template <int EPI>
__global__ __launch_bounds__(256) void k_gemm(const u16* __restrict__ A,
                                              const u16* __restrict__ Bt,
                                              const float* __restrict__ bias,
                                              float* __restrict__ outp,
                                              u16* __restrict__ q_out,
                                              u16* __restrict__ k_out,
                                              u16* __restrict__ vt_out,
                                              int K, int nIter) {
  __shared__ u16 As[2][4096];
  __shared__ u16 Bs[2][4096];
  int tid = threadIdx.x, w = tid >> 6, l = tid & 63;
  int r = l & 15, qd = l >> 4;
  int id = blockIdx.x;
  int xcd = id & 7, s0 = id >> 3;
  int mBlk = xcd * 8 + (s0 & 7);
  int nBlk = s0 >> 3;
  f32x4 acc[4][4] = {};

  const u16* ga[2]; const u16* gb[2]; int lgrp[2];
#pragma unroll
  for (int qq = 0; qq < 2; ++qq) {
    int grp = 2 * w + qq;
    int rowA = mBlk * 128 + grp * 16 + (l >> 2);
    int rowB = nBlk * 128 + grp * 16 + (l >> 2);
    int kcol = (l & 3) * 8;
    ga[qq] = A + (size_t)rowA * K + kcol;
    gb[qq] = Bt + (size_t)rowB * K + kcol;
    lgrp[qq] = grp * 512;
  }
  int aoff = ((w & 1) * 4) * 512 + r * 32 + qd * 8;
  int boff = ((w >> 1) * 4) * 512 + r * 32 + qd * 8;

  auto stageg = [&](int kt, int buf) {
#pragma unroll
    for (int qq = 0; qq < 2; ++qq) {
      gll16(ga[qq] + kt * 32, As[buf] + lgrp[qq]);
      gll16(gb[qq] + kt * 32, Bs[buf] + lgrp[qq]);
    }
  };

  stageg(0, 0);
  __syncthreads();  // buf0 visible

  for (int kt = 0; kt < nIter; ++kt) {
    int cur = kt & 1;
    if (kt + 1 < nIter) stageg(kt + 1, cur ^ 1);  // prefetch flies under compute
    s16x8 af[4], bf[4];
#pragma unroll
    for (int i = 0; i < 4; ++i) af[i] = *(const s16x8*)(As[cur] + aoff + i * 512);
#pragma unroll
    for (int j = 0; j < 4; ++j) bf[j] = *(const s16x8*)(Bs[cur] + boff + j * 512);
#pragma unroll
    for (int i = 0; i < 4; ++i)
#pragma unroll
      for (int j = 0; j < 4; ++j) acc[i][j] = mfma16(af[i], bf[j], acc[i][j]);
    __syncthreads();  // reads of cur done + prefetch into cur^1 landed
  }

  const float QSCALE = 0.125f * 1.44269504088896f;  // folded into q for exp2-domain attn
  int rowBase = mBlk * 128 + (w & 1) * 64;
  int colBase = nBlk * 128 + (w >> 1) * 64;
#pragma unroll
  for (int i = 0; i < 4; ++i) {
#pragma unroll
    for (int j = 0; j < 4; ++j) {
      int col = colBase + j * 16 + r;
      float bv = bias[col];
      float vv[4];
#pragma unroll
      for (int g = 0; g < 4; ++g) vv[g] = acc[i][j][g] + bv;
      int row0 = rowBase + i * 16 + qd * 4;  // rows row0..row0+3 (same 2048-block)
      if (EPI == 0) {
        int which = col >> 10;
        int rem = col & 1023;
        int hh = rem >> 6, dd = rem & 63;
        int bb = row0 >> 11, tt0 = row0 & 2047;
        if (which == 2) {
          // v -> [BH][D][T], 4 consecutive t: one 8B store
          u16x4 pk;
#pragma unroll
          for (int g = 0; g < 4; ++g) pk[g] = f2bf(vv[g]);
          *(u16x4*)(vt_out + (((size_t)(bb * 16 + hh)) * 64 + dd) * 2048 + tt0) = pk;
        } else {
          u16* base = (which == 0) ? q_out : k_out;
#pragma unroll
          for (int g = 0; g < 4; ++g) {
            float v = vv[g];
            if (which == 0) v *= QSCALE;
            base[(((size_t)(bb * 16 + hh)) * 2048 + tt0 + g) * 64 + dd] = f2bf(v);
          }
        }
      } else {
#pragma unroll
        for (int g = 0; g < 4; ++g)
          outp[(size_t)(row0 + g) * 1024 + col] = vv[g];
      }
    }
  }
}

// ---------------- flash attention v7 ----------------
// grid (8, B*H), 256 thr. Block bx handles FOUR 64-row q-chunks {bx,15-bx,16+bx,31-bx}
// (Sum n = 66, balanced). Wave w owns rows [16w,16w+16) of EACH chunk -> 64 q-rows/wave:
// kf/vf LDS reads amortized over 64 q-rows. S^T=mfma(kf,qf), static-max softmax,
// l via ones-MFMA, O^T=mfma(vf,pa).
// v7: TRIPLE-buffered K/V staging with counted vmcnt(4) + raw s_barrier (T4):
// prefetch runs 2 tiles deep, so the end-of-tile barrier drains only tile kt+1's
// 4 loads while kt+2's stay in flight -> no full vmcnt(0) drain per tile.
// s_setprio(1) around the QK and PV MFMA bursts (T5).
// LDS = 24K(Ks) + 24K(Vs) + 32K(Ps) = 80 KiB -> still 2 blocks/CU.
__global__ __launch_bounds__(256, 2) void k_attn(const u16* __restrict__ qg,
                                                 const u16* __restrict__ kg,
                                                 const u16* __restrict__ vtg,
                                                 u16* __restrict__ yg) {
  __shared__ u16 Ks[3][64 * 64];   // [buf][row][8chunk ^ (row&7)]
  __shared__ u16 Vs[3][64 * 64];   // [buf][d]  [8chunk ^ (d&7)]
  __shared__ u16 Ps[4][64 * 64];   // [wave][c*16 + r][col ^ ((r&7)*8)]

  int bh = blockIdx.y, bb = bh >> 4, hh = bh & 15;
  int bx = blockIdx.x;  // 0..7
  int tid = threadIdx.x, w = tid >> 6, l = tid & 63;
  int r = l & 15, qd = l >> 4;
  int psw = (r & 7) * 8;

  const int chunk[4] = {bx, 15 - bx, 16 + bx, 31 - bx};
  const int nend[4]  = {bx + 1, 16 - bx, 17 + bx, 32 - bx};
  int nmax = 32 - bx;
  int qloc = w * 16 + r;  // within-chunk q row owned by lane r

  // Q b-fragments (q pre-scaled by 1/8*log2e at GEMM0 epilogue)
  s16x8 qf[4][2];
#pragma unroll
  for (int c = 0; c < 4; ++c) {
    int qbase = chunk[c] * 64 + w * 16;
#pragma unroll
    for (int s = 0; s < 2; ++s)
      qf[c][s] = *(const s16x8*)(qg + ((size_t)bh * 2048 + qbase + r) * 64 + s * 32 + qd * 8);
  }

  s16x8 onesf;
#pragma unroll
  for (int e = 0; e < 8; ++e) onesf[e] = (short)0x3F80;  // bf16 1.0

  f32x4 o[4][4] = {};    // O^T: o[c][j][g] = O[q=qbase_c + r][d = 16j + 4qd + g]
  f32x4 lacc[4] = {};    // ones-MFMA row-sum

  // staging lane geometry
  int rl = l >> 3;
  int cg = (l & 7) ^ rl;
  const u16* kbase = kg + (size_t)bh * 2048 * 64;
  const u16* vbase = vtg + (size_t)bh * 64 * 2048;

  auto stage = [&](int kt, int buf) {
    int kk0 = kt * 64;
#pragma unroll
    for (int p = 0; p < 2; ++p) {
      int row = p * 32 + w * 8 + rl;
      gll16(kbase + ((size_t)(kk0 + row)) * 64 + cg * 8, Ks[buf] + p * 2048 + w * 512);
      gll16(vbase + (size_t)row * 2048 + kk0 + cg * 8, Vs[buf] + p * 2048 + w * 512);
    }
  };

  // prologue: fill buffers 0 and 1 (8 loads outstanding), wait for tile 0 only
  stage(0, 0);
  stage(1, 1);
  asm volatile("s_waitcnt vmcnt(4)" ::: "memory");
  __builtin_amdgcn_s_barrier();

  int cur = 0, b2 = 2;
  for (int kt = 0; kt < nmax; ++kt) {
    // stage tile kt+2 (clamped at the tail so exactly 8 loads stay outstanding;
    // duplicate tail stages land in the unused rotating buffer -> harmless)
    int nk = kt + 2;
    nk = (nk < nmax) ? nk : (nmax - 1);
    stage(nk, b2);

    // ---- QK^T for all active chunks; kf read once, feeds up to 4 chunks ----
    f32x4 sacc[4][4];
#pragma unroll
    for (int c = 0; c < 4; ++c)
      if (kt < nend[c])
#pragma unroll
        for (int j = 0; j < 4; ++j) sacc[c][j] = f32x4{0.f, 0.f, 0.f, 0.f};
    __builtin_amdgcn_s_setprio(1);
#pragma unroll
    for (int s = 0; s < 2; ++s) {
#pragma unroll
      for (int j = 0; j < 4; ++j) {
        s16x8 kf = *(const s16x8*)(Ks[cur] + (16 * j + r) * 64 + ((s * 4 + qd) ^ (r & 7)) * 8);
#pragma unroll
        for (int c = 0; c < 4; ++c)
          if (kt < nend[c]) sacc[c][j] = mfma16(kf, qf[c][s], sacc[c][j]);
      }
    }
    __builtin_amdgcn_s_setprio(0);

    // ---- softmax + P store (chunk-private Ps rows -> no WAR fence needed) ----
#pragma unroll
    for (int c = 0; c < 4; ++c) {
      if (kt >= nend[c]) continue;
      bool needMask = (kt == chunk[c]);  // diagonal tile
#pragma unroll
      for (int j = 0; j < 4; ++j) {
        float p0, p1, p2, p3;  // k-local = 16j + 4qd + g
        if (needMask) {
          int kb0 = 16 * j + 4 * qd;
          p0 = (kb0 + 0 > qloc) ? 0.f : __builtin_amdgcn_exp2f(sacc[c][j][0]);
          p1 = (kb0 + 1 > qloc) ? 0.f : __builtin_amdgcn_exp2f(sacc[c][j][1]);
          p2 = (kb0 + 2 > qloc) ? 0.f : __builtin_amdgcn_exp2f(sacc[c][j][2]);
          p3 = (kb0 + 3 > qloc) ? 0.f : __builtin_amdgcn_exp2f(sacc[c][j][3]);
        } else {
          p0 = __builtin_amdgcn_exp2f(sacc[c][j][0]);
          p1 = __builtin_amdgcn_exp2f(sacc[c][j][1]);
          p2 = __builtin_amdgcn_exp2f(sacc[c][j][2]);
          p3 = __builtin_amdgcn_exp2f(sacc[c][j][3]);
        }
        uint2 pk;
        pk.x = pk_trunc(p1, p0);
        pk.y = pk_trunc(p3, p2);
        *(uint2*)(Ps[w] + (c * 16 + r) * 64 + ((j * 16 + qd * 4) ^ psw)) = pk;
      }
    }
    lds_fence();  // P stores visible to own wave's reads

    // ---- PV burst: vf read once per (s,j), shared by all active chunks ----
    __builtin_amdgcn_s_setprio(1);
#pragma unroll
    for (int s = 0; s < 2; ++s) {
      s16x8 pa[4];
#pragma unroll
      for (int c = 0; c < 4; ++c)
        if (kt < nend[c]) {
          pa[c] = *(const s16x8*)(Ps[w] + (c * 16 + r) * 64 + ((s * 32 + qd * 8) ^ psw));
          lacc[c] = mfma16(onesf, pa[c], lacc[c]);
        }
#pragma unroll
      for (int j = 0; j < 4; ++j) {
        s16x8 vf = *(const s16x8*)(Vs[cur] + (16 * j + r) * 64 + ((s * 4 + qd) ^ (r & 7)) * 8);
#pragma unroll
        for (int c = 0; c < 4; ++c)
          if (kt < nend[c]) o[c][j] = mfma16(vf, pa[c], o[c][j]);
      }
    }
    __builtin_amdgcn_s_setprio(0);

    // counted drain: tile kt+1's 4 loads (oldest) must land; kt+2's 4 stay in flight
    asm volatile("s_waitcnt vmcnt(4)" ::: "memory");
    __builtin_amdgcn_s_barrier();
    cur = (cur == 2) ? 0 : cur + 1;
    b2 = (b2 == 2) ? 0 : b2 + 1;
  }

  // epilogue: lane (r,qd), chunk c: y[q = qbase_c + r][d = 16j + 4qd + g], packed x4
#pragma unroll
  for (int c = 0; c < 4; ++c) {
    int qbase = chunk[c] * 64 + w * 16;
    float inv = 1.0f / lacc[c][0];
    size_t rowoff = ((size_t)bb * 2048 + qbase + r) * 1024 + hh * 64;
#pragma unroll
    for (int j = 0; j < 4; ++j) {
      u16x4 yv;
      yv[0] = f2bf(o[c][j][0] * inv);
      yv[1] = f2bf(o[c][j][1] * inv);
      yv[2] = f2bf(o[c][j][2] * inv);
      yv[3] = f2bf(o[c][j][3] * inv);
      *(u16x4*)(yg + rowoff + 16 * j + 4 * qd) = yv;
    }
  }
}

// ---------------- launch ----------------
extern "C" void kernel_launch(void* const* d_in, const int* in_sizes, int n_in,
                              void* d_out, int out_size, void* d_ws, size_t ws_size,
                              hipStream_t stream) {
  const float* x      = (const float*)d_in[0];
  const float* w_attn = (const float*)d_in[1];
  const float* b_attn = (const float*)d_in[2];
  const float* w_proj = (const float*)d_in[3];
  const float* b_proj = (const float*)d_in[4];
  float* out = (float*)d_out;

  char* ws = (char*)d_ws;
  size_t off = 0;
  auto alloc = [&](size_t bytes) -> void* {
    void* p = ws + off;
    off += (bytes + 255) & ~(size_t)255;
    return p;
  };
  const size_t BT = 8192, C = 1024;
  u16* xb  = (u16*)alloc(BT * C * 2);          // x bf16; reused as y
  u16* waT = (u16*)alloc(3072 * 1024 * 2);
  u16* wpT = (u16*)alloc(1024 * 1024 * 2);
  u16* qb  = (u16*)alloc(BT * C * 2);          // [BH][T][D], q pre-scaled
  u16* kb  = (u16*)alloc(BT * C * 2);          // [BH][T][D]
  u16* vtb = (u16*)alloc(BT * C * 2);          // [BH][D][T] (written by GEMM0 directly)
  (void)ws_size; (void)in_sizes; (void)n_in; (void)out_size;

  k_convert_x<<<4096, 256, 0, stream>>>(x, xb);
  k_transpose_w<<<dim3(96, 32), 256, 0, stream>>>(w_attn, waT, 1024, 3072);
  k_transpose_w<<<dim3(32, 32), 256, 0, stream>>>(w_proj, wpT, 1024, 1024);
  k_gemm<0><<<1536, 256, 0, stream>>>(xb, waT, b_attn, nullptr, qb, kb, vtb, 1024, 32);
  k_attn<<<dim3(8, 64), 256, 0, stream>>>(qb, kb, vtb, xb /* y reuses xb */);
  k_gemm<1><<<512, 256, 0, stream>>>(xb, wpT, b_proj, out, nullptr, nullptr, nullptr, 1024, 32);
}

// Round 2
// 263.959 us; speedup vs baseline: 1.0212x; 1.0212x over previous
//
#include <hip/hip_runtime.h>
#include <math.h>

// ---------------- types / helpers ----------------
typedef short s16x8 __attribute__((ext_vector_type(8)));     // 8 bf16 in 4 VGPRs
typedef unsigned short u16;
typedef unsigned short u16x4 __attribute__((ext_vector_type(4)));
typedef float f32x4 __attribute__((ext_vector_type(4)));

__device__ __forceinline__ f32x4 mfma16(s16x8 a, s16x8 b, f32x4 c) {
  return __builtin_amdgcn_mfma_f32_16x16x32_bf16(a, b, c, 0, 0, 0);
}

// fp32 -> bf16 bits, round-to-nearest-even
__device__ __forceinline__ u16 f2bf(float f) {
  unsigned u = __builtin_bit_cast(unsigned, f);
  u = (u + 0x7fffu + ((u >> 16) & 1u)) >> 16;
  return (u16)u;
}

// pack two fp32 -> two truncated bf16 in one v_perm
__device__ __forceinline__ unsigned pk_trunc(float hi, float lo) {
  return __builtin_amdgcn_perm(__builtin_bit_cast(unsigned, hi),
                               __builtin_bit_cast(unsigned, lo), 0x07060302u);
}

// async global->LDS, 16B per lane; lds base wave-uniform, lane i lands at base + i*16
__device__ __forceinline__ void gll16(const void* g, void* l) {
  __builtin_amdgcn_global_load_lds((__attribute__((address_space(1))) void*)(void*)g,
                                   (__attribute__((address_space(3))) void*)l,
                                   16, 0, 0);
}

// wave-local LDS fence: drain DS queue + compiler ordering (no workgroup barrier)
__device__ __forceinline__ void lds_fence() {
  asm volatile("s_waitcnt lgkmcnt(0)" ::: "memory");
}

// ---------------- layout/convert kernels ----------------
__global__ __launch_bounds__(256) void k_convert_x(const float* __restrict__ x,
                                                   u16* __restrict__ xb) {
  int i = (blockIdx.x * 256 + threadIdx.x) * 8;
  const float4* xv = (const float4*)(x + i);
  float4 a = xv[0], b = xv[1];
  union { s16x8 v; u16 s[8]; } r;
  r.s[0] = f2bf(a.x); r.s[1] = f2bf(a.y); r.s[2] = f2bf(a.z); r.s[3] = f2bf(a.w);
  r.s[4] = f2bf(b.x); r.s[5] = f2bf(b.y); r.s[6] = f2bf(b.z); r.s[7] = f2bf(b.w);
  *(s16x8*)(xb + i) = r.v;
}

// in: fp32 [R][C]  ->  out: bf16 [C][R]
__global__ __launch_bounds__(256) void k_transpose_w(const float* __restrict__ in,
                                                     u16* __restrict__ out, int R, int C) {
  __shared__ float tile[32][33];
  int c0 = blockIdx.x * 32, r0 = blockIdx.y * 32;
  int tx = threadIdx.x & 31, ty = threadIdx.x >> 5;  // 32 x 8
#pragma unroll
  for (int s = 0; s < 4; ++s)
    tile[ty + 8 * s][tx] = in[(size_t)(r0 + ty + 8 * s) * C + c0 + tx];
  __syncthreads();
#pragma unroll
  for (int s = 0; s < 4; ++s)
    out[(size_t)(c0 + ty + 8 * s) * R + r0 + tx] = f2bf(tile[tx][ty + 8 * s]);
}

// ---------------- GEMM: C = A[M,K] * Bt[N,K]^T + bias ----------------
// 1D grid, XCD-aware swizzle. Double-buffered LDS staging (global_load_lds width=16).
// EPI 0: scatter q (scaled), k as [BH][T][D]; v transposed to [BH][D][T].
template <int EPI>
__global__ __launch_bounds__(256) void k_gemm(const u16* __restrict__ A,
                                              const u16* __restrict__ Bt,
                                              const float* __restrict__ bias,
                                              float* __restrict__ outp,
                                              u16* __restrict__ q_out,
                                              u16* __restrict__ k_out,
                                              u16* __restrict__ vt_out,
                                              int K, int nIter) {
  __shared__ u16 As[2][4096];
  __shared__ u16 Bs[2][4096];
  int tid = threadIdx.x, w = tid >> 6, l = tid & 63;
  int r = l & 15, qd = l >> 4;
  int id = blockIdx.x;
  int xcd = id & 7, s0 = id >> 3;
  int mBlk = xcd * 8 + (s0 & 7);
  int nBlk = s0 >> 3;
  f32x4 acc[4][4] = {};

  const u16* ga[2]; const u16* gb[2]; int lgrp[2];
#pragma unroll
  for (int qq = 0; qq < 2; ++qq) {
    int grp = 2 * w + qq;
    int rowA = mBlk * 128 + grp * 16 + (l >> 2);
    int rowB = nBlk * 128 + grp * 16 + (l >> 2);
    int kcol = (l & 3) * 8;
    ga[qq] = A + (size_t)rowA * K + kcol;
    gb[qq] = Bt + (size_t)rowB * K + kcol;
    lgrp[qq] = grp * 512;
  }
  int aoff = ((w & 1) * 4) * 512 + r * 32 + qd * 8;
  int boff = ((w >> 1) * 4) * 512 + r * 32 + qd * 8;

  auto stageg = [&](int kt, int buf) {
#pragma unroll
    for (int qq = 0; qq < 2; ++qq) {
      gll16(ga[qq] + kt * 32, As[buf] + lgrp[qq]);
      gll16(gb[qq] + kt * 32, Bs[buf] + lgrp[qq]);
    }
  };

  stageg(0, 0);
  __syncthreads();  // buf0 visible

  for (int kt = 0; kt < nIter; ++kt) {
    int cur = kt & 1;
    if (kt + 1 < nIter) stageg(kt + 1, cur ^ 1);  // prefetch flies under compute
    s16x8 af[4], bf[4];
#pragma unroll
    for (int i = 0; i < 4; ++i) af[i] = *(const s16x8*)(As[cur] + aoff + i * 512);
#pragma unroll
    for (int j = 0; j < 4; ++j) bf[j] = *(const s16x8*)(Bs[cur] + boff + j * 512);
#pragma unroll
    for (int i = 0; i < 4; ++i)
#pragma unroll
      for (int j = 0; j < 4; ++j) acc[i][j] = mfma16(af[i], bf[j], acc[i][j]);
    __syncthreads();  // reads of cur done + prefetch into cur^1 landed
  }

  const float QSCALE = 0.125f * 1.44269504088896f;  // folded into q for exp2-domain attn
  int rowBase = mBlk * 128 + (w & 1) * 64;
  int colBase = nBlk * 128 + (w >> 1) * 64;
#pragma unroll
  for (int i = 0; i < 4; ++i) {
#pragma unroll
    for (int j = 0; j < 4; ++j) {
      int col = colBase + j * 16 + r;
      float bv = bias[col];
      float vv[4];
#pragma unroll
      for (int g = 0; g < 4; ++g) vv[g] = acc[i][j][g] + bv;
      int row0 = rowBase + i * 16 + qd * 4;  // rows row0..row0+3 (same 2048-block)
      if (EPI == 0) {
        int which = col >> 10;
        int rem = col & 1023;
        int hh = rem >> 6, dd = rem & 63;
        int bb = row0 >> 11, tt0 = row0 & 2047;
        if (which == 2) {
          // v -> [BH][D][T], 4 consecutive t: one 8B store
          u16x4 pk;
#pragma unroll
          for (int g = 0; g < 4; ++g) pk[g] = f2bf(vv[g]);
          *(u16x4*)(vt_out + (((size_t)(bb * 16 + hh)) * 64 + dd) * 2048 + tt0) = pk;
        } else {
          u16* base = (which == 0) ? q_out : k_out;
#pragma unroll
          for (int g = 0; g < 4; ++g) {
            float v = vv[g];
            if (which == 0) v *= QSCALE;
            base[(((size_t)(bb * 16 + hh)) * 2048 + tt0 + g) * 64 + dd] = f2bf(v);
          }
        }
      } else {
#pragma unroll
        for (int g = 0; g < 4; ++g)
          outp[(size_t)(row0 + g) * 1024 + col] = vv[g];
      }
    }
  }
}

// ---------------- flash attention v8 ----------------
// 1D grid 512, 256 thr. Head-grouped XCD swizzle: id&7 == bh&7, so all 8 bx-blocks
// of a head share one XCD's L2 (8 heads/XCD ~ 4MB K/V). Block bx handles FOUR
// 64-row q-chunks {bx,15-bx,16+bx,31-bx} (sum n = 66, balanced). Wave w owns rows
// [16w,16w+16) of EACH chunk.
// v8: CROSS-TILE SOFTWARE PIPELINE. Iteration kt runs PV(kt) and QK(kt+1) in one
// barrier-free region (independent data: Ps/Vs[kt] vs Ks[kt+1]) -> two MFMA
// streams interleave and the P-store->fence->pa-read round trip is off the
// critical path. Triple-buffered K/V holds the 3 live tiles {kt, kt+1, kt+2};
// stage(kt+2) issued at iter top lands well before the iter-end __syncthreads.
// LDS = 24K(Ks)+24K(Vs)+32K(Ps) = 80 KiB -> 2 blocks/CU.
__global__ __launch_bounds__(256, 2) void k_attn(const u16* __restrict__ qg,
                                                 const u16* __restrict__ kg,
                                                 const u16* __restrict__ vtg,
                                                 u16* __restrict__ yg) {
  __shared__ u16 Ks[3][64 * 64];   // [buf][row][8chunk ^ (row&7)]
  __shared__ u16 Vs[3][64 * 64];   // [buf][d]  [8chunk ^ (d&7)]
  __shared__ u16 Ps[4][64 * 64];   // [wave][c*16 + r][col ^ ((r&7)*8)]

  int id = blockIdx.x;
  int xcd = id & 7;                // == bh & 7 -> same-head blocks share an XCD
  int slot = id >> 3;              // 0..63
  int bx = slot & 7;               // 0..7
  int bh = ((slot >> 3) << 3) | xcd;
  int bb = bh >> 4, hh = bh & 15;
  int tid = threadIdx.x, w = tid >> 6, l = tid & 63;
  int r = l & 15, qd = l >> 4;
  int psw = (r & 7) * 8;

  const int chunk[4] = {bx, 15 - bx, 16 + bx, 31 - bx};
  const int nend[4]  = {bx + 1, 16 - bx, 17 + bx, 32 - bx};
  int nmax = 32 - bx;
  int qloc = w * 16 + r;  // within-chunk q row owned by lane r

  // Q b-fragments (q pre-scaled by 1/8*log2e at GEMM0 epilogue)
  s16x8 qf[4][2];
#pragma unroll
  for (int c = 0; c < 4; ++c) {
    int qbase = chunk[c] * 64 + w * 16;
#pragma unroll
    for (int s = 0; s < 2; ++s)
      qf[c][s] = *(const s16x8*)(qg + ((size_t)bh * 2048 + qbase + r) * 64 + s * 32 + qd * 8);
  }

  s16x8 onesf;
#pragma unroll
  for (int e = 0; e < 8; ++e) onesf[e] = (short)0x3F80;  // bf16 1.0

  f32x4 o[4][4] = {};    // O^T: o[c][j][g] = O[q=qbase_c + r][d = 16j + 4qd + g]
  f32x4 lacc[4] = {};    // ones-MFMA row-sum

  // staging lane geometry
  int rl = l >> 3;
  int cg = (l & 7) ^ rl;
  const u16* kbase = kg + (size_t)bh * 2048 * 64;
  const u16* vbase = vtg + (size_t)bh * 64 * 2048;

  auto stage = [&](int kt, int buf) {
    int kk0 = kt * 64;
#pragma unroll
    for (int p = 0; p < 2; ++p) {
      int row = p * 32 + w * 8 + rl;
      gll16(kbase + ((size_t)(kk0 + row)) * 64 + cg * 8, Ks[buf] + p * 2048 + w * 512);
      gll16(vbase + (size_t)row * 2048 + kk0 + cg * 8, Vs[buf] + p * 2048 + w * 512);
    }
  };

  // QK^T for tile kt into Ps (exp2-domain softmax, causal mask on diagonal tile)
  auto qk_smax = [&](int kt, int buf) {
    f32x4 sacc[4][4];
#pragma unroll
    for (int c = 0; c < 4; ++c)
      if (kt < nend[c])
#pragma unroll
        for (int j = 0; j < 4; ++j) sacc[c][j] = f32x4{0.f, 0.f, 0.f, 0.f};
    __builtin_amdgcn_s_setprio(1);
#pragma unroll
    for (int s = 0; s < 2; ++s) {
#pragma unroll
      for (int j = 0; j < 4; ++j) {
        s16x8 kf = *(const s16x8*)(Ks[buf] + (16 * j + r) * 64 + ((s * 4 + qd) ^ (r & 7)) * 8);
#pragma unroll
        for (int c = 0; c < 4; ++c)
          if (kt < nend[c]) sacc[c][j] = mfma16(kf, qf[c][s], sacc[c][j]);
      }
    }
    __builtin_amdgcn_s_setprio(0);
#pragma unroll
    for (int c = 0; c < 4; ++c) {
      if (kt >= nend[c]) continue;
      bool needMask = (kt == chunk[c]);  // diagonal tile
#pragma unroll
      for (int j = 0; j < 4; ++j) {
        float p0, p1, p2, p3;  // k-local = 16j + 4qd + g
        if (needMask) {
          int kb0 = 16 * j + 4 * qd;
          p0 = (kb0 + 0 > qloc) ? 0.f : __builtin_amdgcn_exp2f(sacc[c][j][0]);
          p1 = (kb0 + 1 > qloc) ? 0.f : __builtin_amdgcn_exp2f(sacc[c][j][1]);
          p2 = (kb0 + 2 > qloc) ? 0.f : __builtin_amdgcn_exp2f(sacc[c][j][2]);
          p3 = (kb0 + 3 > qloc) ? 0.f : __builtin_amdgcn_exp2f(sacc[c][j][3]);
        } else {
          p0 = __builtin_amdgcn_exp2f(sacc[c][j][0]);
          p1 = __builtin_amdgcn_exp2f(sacc[c][j][1]);
          p2 = __builtin_amdgcn_exp2f(sacc[c][j][2]);
          p3 = __builtin_amdgcn_exp2f(sacc[c][j][3]);
        }
        uint2 pk;
        pk.x = pk_trunc(p1, p0);
        pk.y = pk_trunc(p3, p2);
        *(uint2*)(Ps[w] + (c * 16 + r) * 64 + ((j * 16 + qd * 4) ^ psw)) = pk;
      }
    }
  };

  // PV for tile kt: reads Ps (written for kt last iteration) + Vs[buf]
  auto pv = [&](int kt, int buf) {
    __builtin_amdgcn_s_setprio(1);
#pragma unroll
    for (int s = 0; s < 2; ++s) {
      s16x8 pa[4];
#pragma unroll
      for (int c = 0; c < 4; ++c)
        if (kt < nend[c]) {
          pa[c] = *(const s16x8*)(Ps[w] + (c * 16 + r) * 64 + ((s * 32 + qd * 8) ^ psw));
          lacc[c] = mfma16(onesf, pa[c], lacc[c]);
        }
#pragma unroll
      for (int j = 0; j < 4; ++j) {
        s16x8 vf = *(const s16x8*)(Vs[buf] + (16 * j + r) * 64 + ((s * 4 + qd) ^ (r & 7)) * 8);
#pragma unroll
        for (int c = 0; c < 4; ++c)
          if (kt < nend[c]) o[c][j] = mfma16(vf, pa[c], o[c][j]);
      }
    }
    __builtin_amdgcn_s_setprio(0);
  };

  // prologue: fill buffers 0,1; publish; prime the pipeline with QK(0)
  stage(0, 0);
  stage(1, 1);
  __syncthreads();
  qk_smax(0, 0);
  lds_fence();  // P(0) visible to own wave's PV reads

  int b0 = 0, b1 = 1, b2 = 2;
  for (int kt = 0; kt < nmax; ++kt) {
    if (kt + 2 < nmax) stage(kt + 2, b2);   // lands during this body; published at barrier
    pv(kt, b0);                             // consumes P(kt), Vs[kt]  (independent of QK below)
    if (kt + 1 < nmax) qk_smax(kt + 1, b1); // produces P(kt+1) from Ks[kt+1]
    __syncthreads();                        // publishes tile kt+2; P stores drained (lgkmcnt 0)
    int t = b0; b0 = b1; b1 = b2; b2 = t;
  }

  // epilogue: lane (r,qd), chunk c: y[q = qbase_c + r][d = 16j + 4qd + g], packed x4
#pragma unroll
  for (int c = 0; c < 4; ++c) {
    int qbase = chunk[c] * 64 + w * 16;
    float inv = 1.0f / lacc[c][0];
    size_t rowoff = ((size_t)bb * 2048 + qbase + r) * 1024 + hh * 64;
#pragma unroll
    for (int j = 0; j < 4; ++j) {
      u16x4 yv;
      yv[0] = f2bf(o[c][j][0] * inv);
      yv[1] = f2bf(o[c][j][1] * inv);
      yv[2] = f2bf(o[c][j][2] * inv);
      yv[3] = f2bf(o[c][j][3] * inv);
      *(u16x4*)(yg + rowoff + 16 * j + 4 * qd) = yv;
    }
  }
}

// ---------------- launch ----------------
extern "C" void kernel_launch(void* const* d_in, const int* in_sizes, int n_in,
                              void* d_out, int out_size, void* d_ws, size_t ws_size,
                              hipStream_t stream) {
  const float* x      = (const float*)d_in[0];
  const float* w_attn = (const float*)d_in[1];
  const float* b_attn = (const float*)d_in[2];
  const float* w_proj = (const float*)d_in[3];
  const float* b_proj = (const float*)d_in[4];
  float* out = (float*)d_out;

  char* ws = (char*)d_ws;
  size_t off = 0;
  auto alloc = [&](size_t bytes) -> void* {
    void* p = ws + off;
    off += (bytes + 255) & ~(size_t)255;
    return p;
  };
  const size_t BT = 8192, C = 1024;
  u16* xb  = (u16*)alloc(BT * C * 2);          // x bf16; reused as y
  u16* waT = (u16*)alloc(3072 * 1024 * 2);
  u16* wpT = (u16*)alloc(1024 * 1024 * 2);
  u16* qb  = (u16*)alloc(BT * C * 2);          // [BH][T][D], q pre-scaled
  u16* kb  = (u16*)alloc(BT * C * 2);          // [BH][T][D]
  u16* vtb = (u16*)alloc(BT * C * 2);          // [BH][D][T] (written by GEMM0 directly)
  (void)ws_size; (void)in_sizes; (void)n_in; (void)out_size;

  k_convert_x<<<4096, 256, 0, stream>>>(x, xb);
  k_transpose_w<<<dim3(96, 32), 256, 0, stream>>>(w_attn, waT, 1024, 3072);
  k_transpose_w<<<dim3(32, 32), 256, 0, stream>>>(w_proj, wpT, 1024, 1024);
  k_gemm<0><<<1536, 256, 0, stream>>>(xb, waT, b_attn, nullptr, qb, kb, vtb, 1024, 32);
  k_attn<<<512, 256, 0, stream>>>(qb, kb, vtb, xb /* y reuses xb */);
  k_gemm<1><<<512, 256, 0, stream>>>(xb, wpT, b_proj, out, nullptr, nullptr, nullptr, 1024, 32);
}

// Round 3
// 245.164 us; speedup vs baseline: 1.0995x; 1.0767x over previous
//
#include <hip/hip_runtime.h>
#include <math.h>

// ---------------- types / helpers ----------------
typedef short s16x8 __attribute__((ext_vector_type(8)));     // 8 bf16 in 4 VGPRs
typedef unsigned short u16;
typedef unsigned short u16x4 __attribute__((ext_vector_type(4)));
typedef float f32x4 __attribute__((ext_vector_type(4)));

__device__ __forceinline__ f32x4 mfma16(s16x8 a, s16x8 b, f32x4 c) {
  return __builtin_amdgcn_mfma_f32_16x16x32_bf16(a, b, c, 0, 0, 0);
}

// fp32 -> bf16 bits, round-to-nearest-even
__device__ __forceinline__ u16 f2bf(float f) {
  unsigned u = __builtin_bit_cast(unsigned, f);
  u = (u + 0x7fffu + ((u >> 16) & 1u)) >> 16;
  return (u16)u;
}

// pack two fp32 -> two truncated bf16 in one v_perm
__device__ __forceinline__ unsigned pk_trunc(float hi, float lo) {
  return __builtin_amdgcn_perm(__builtin_bit_cast(unsigned, hi),
                               __builtin_bit_cast(unsigned, lo), 0x07060302u);
}

__device__ __forceinline__ s16x8 mk_pa(unsigned a, unsigned b, unsigned c, unsigned d) {
  union { unsigned u[4]; s16x8 h; } t;
  t.u[0] = a; t.u[1] = b; t.u[2] = c; t.u[3] = d;
  return t.h;
}

// async global->LDS, 16B per lane; lds base wave-uniform, lane i lands at base + i*16
__device__ __forceinline__ void gll16(const void* g, void* l) {
  __builtin_amdgcn_global_load_lds((__attribute__((address_space(1))) void*)(void*)g,
                                   (__attribute__((address_space(3))) void*)l,
                                   16, 0, 0);
}

// ---------------- layout/convert kernels ----------------
__global__ __launch_bounds__(256) void k_convert_x(const float* __restrict__ x,
                                                   u16* __restrict__ xb) {
  int i = (blockIdx.x * 256 + threadIdx.x) * 8;
  const float4* xv = (const float4*)(x + i);
  float4 a = xv[0], b = xv[1];
  union { s16x8 v; u16 s[8]; } r;
  r.s[0] = f2bf(a.x); r.s[1] = f2bf(a.y); r.s[2] = f2bf(a.z); r.s[3] = f2bf(a.w);
  r.s[4] = f2bf(b.x); r.s[5] = f2bf(b.y); r.s[6] = f2bf(b.z); r.s[7] = f2bf(b.w);
  *(s16x8*)(xb + i) = r.v;
}

// in: fp32 [R][C]  ->  out: bf16 [C][R]
__global__ __launch_bounds__(256) void k_transpose_w(const float* __restrict__ in,
                                                     u16* __restrict__ out, int R, int C) {
  __shared__ float tile[32][33];
  int c0 = blockIdx.x * 32, r0 = blockIdx.y * 32;
  int tx = threadIdx.x & 31, ty = threadIdx.x >> 5;  // 32 x 8
#pragma unroll
  for (int s = 0; s < 4; ++s)
    tile[ty + 8 * s][tx] = in[(size_t)(r0 + ty + 8 * s) * C + c0 + tx];
  __syncthreads();
#pragma unroll
  for (int s = 0; s < 4; ++s)
    out[(size_t)(c0 + ty + 8 * s) * R + r0 + tx] = f2bf(tile[tx][ty + 8 * s]);
}

// ---------------- GEMM: C = A[M,K] * Bt[N,K]^T + bias ----------------
// 1D grid, XCD-aware swizzle. Double-buffered LDS staging (global_load_lds width=16).
// EPI 0: scatter q (scaled), k as [BH][T][D]; v transposed to [BH][D][T].
template <int EPI>
__global__ __launch_bounds__(256) void k_gemm(const u16* __restrict__ A,
                                              const u16* __restrict__ Bt,
                                              const float* __restrict__ bias,
                                              float* __restrict__ outp,
                                              u16* __restrict__ q_out,
                                              u16* __restrict__ k_out,
                                              u16* __restrict__ vt_out,
                                              int K, int nIter) {
  __shared__ u16 As[2][4096];
  __shared__ u16 Bs[2][4096];
  int tid = threadIdx.x, w = tid >> 6, l = tid & 63;
  int r = l & 15, qd = l >> 4;
  int id = blockIdx.x;
  int xcd = id & 7, s0 = id >> 3;
  int mBlk = xcd * 8 + (s0 & 7);
  int nBlk = s0 >> 3;
  f32x4 acc[4][4] = {};

  const u16* ga[2]; const u16* gb[2]; int lgrp[2];
#pragma unroll
  for (int qq = 0; qq < 2; ++qq) {
    int grp = 2 * w + qq;
    int rowA = mBlk * 128 + grp * 16 + (l >> 2);
    int rowB = nBlk * 128 + grp * 16 + (l >> 2);
    int kcol = (l & 3) * 8;
    ga[qq] = A + (size_t)rowA * K + kcol;
    gb[qq] = Bt + (size_t)rowB * K + kcol;
    lgrp[qq] = grp * 512;
  }
  int aoff = ((w & 1) * 4) * 512 + r * 32 + qd * 8;
  int boff = ((w >> 1) * 4) * 512 + r * 32 + qd * 8;

  auto stageg = [&](int kt, int buf) {
#pragma unroll
    for (int qq = 0; qq < 2; ++qq) {
      gll16(ga[qq] + kt * 32, As[buf] + lgrp[qq]);
      gll16(gb[qq] + kt * 32, Bs[buf] + lgrp[qq]);
    }
  };

  stageg(0, 0);
  __syncthreads();  // buf0 visible

  for (int kt = 0; kt < nIter; ++kt) {
    int cur = kt & 1;
    if (kt + 1 < nIter) stageg(kt + 1, cur ^ 1);  // prefetch flies under compute
    s16x8 af[4], bf[4];
#pragma unroll
    for (int i = 0; i < 4; ++i) af[i] = *(const s16x8*)(As[cur] + aoff + i * 512);
#pragma unroll
    for (int j = 0; j < 4; ++j) bf[j] = *(const s16x8*)(Bs[cur] + boff + j * 512);
#pragma unroll
    for (int i = 0; i < 4; ++i)
#pragma unroll
      for (int j = 0; j < 4; ++j) acc[i][j] = mfma16(af[i], bf[j], acc[i][j]);
    __syncthreads();  // reads of cur done + prefetch into cur^1 landed
  }

  const float QSCALE = 0.125f * 1.44269504088896f;  // folded into q for exp2-domain attn
  int rowBase = mBlk * 128 + (w & 1) * 64;
  int colBase = nBlk * 128 + (w >> 1) * 64;
#pragma unroll
  for (int i = 0; i < 4; ++i) {
#pragma unroll
    for (int j = 0; j < 4; ++j) {
      int col = colBase + j * 16 + r;
      float bv = bias[col];
      float vv[4];
#pragma unroll
      for (int g = 0; g < 4; ++g) vv[g] = acc[i][j][g] + bv;
      int row0 = rowBase + i * 16 + qd * 4;  // rows row0..row0+3 (same 2048-block)
      if (EPI == 0) {
        int which = col >> 10;
        int rem = col & 1023;
        int hh = rem >> 6, dd = rem & 63;
        int bb = row0 >> 11, tt0 = row0 & 2047;
        if (which == 2) {
          // v -> [BH][D][T], 4 consecutive t: one 8B store
          u16x4 pk;
#pragma unroll
          for (int g = 0; g < 4; ++g) pk[g] = f2bf(vv[g]);
          *(u16x4*)(vt_out + (((size_t)(bb * 16 + hh)) * 64 + dd) * 2048 + tt0) = pk;
        } else {
          u16* base = (which == 0) ? q_out : k_out;
#pragma unroll
          for (int g = 0; g < 4; ++g) {
            float v = vv[g];
            if (which == 0) v *= QSCALE;
            base[(((size_t)(bb * 16 + hh)) * 2048 + tt0 + g) * 64 + dd] = f2bf(v);
          }
        }
      } else {
#pragma unroll
        for (int g = 0; g < 4; ++g)
          outp[(size_t)(row0 + g) * 1024 + col] = vv[g];
      }
    }
  }
}

// ---------------- flash attention v9 ----------------
// 1D grid 1024, 256 thr. Head-grouped XCD swizzle: id&7 == bh&7 (16 blocks of a
// head share one XCD's L2). Block bx in [0,16) handles TWO 64-row q-chunks
// {bx, 31-bx}: MFMA work = (bx+1)+(32-bx) = 33 tiles -> balanced. Wave w owns
// rows [16w,16w+16) of each chunk.
// v9: IN-REGISTER P. The QK->PV transpose is a 4-lane exchange among lanes
// {r, r+16, r+32, r+48}: after packing S rows to bf16 pairs, one
// v_permlane32_swap + v_permlane16_swap per register pair lands P directly in
// the PV B-fragment layout. The Ps LDS buffer (32KB), its ds_write/ds_read
// round trip and lgkmcnt fence are gone. LDS = dbuf K/V = 32KB -> 4 blocks/CU
// (was 2); VGPR capped at 128 by __launch_bounds__(256,4). The per-tile serial
// chain (kf -> QK -> exp2 -> permlane -> PV) is hidden by 4 waves/SIMD of TLP.
__global__ __launch_bounds__(256, 4) void k_attn(const u16* __restrict__ qg,
                                                 const u16* __restrict__ kg,
                                                 const u16* __restrict__ vtg,
                                                 u16* __restrict__ yg) {
  __shared__ u16 Ks[2][64 * 64];   // [buf][row][8chunk ^ (row&7)]
  __shared__ u16 Vs[2][64 * 64];   // [buf][d]  [8chunk ^ (d&7)]

  int id = blockIdx.x;
  int xcd = id & 7;                // == bh & 7 -> same-head blocks share an XCD
  int slot = id >> 3;              // 0..127
  int bx = slot & 15;              // 0..15
  int bh = ((slot >> 4) << 3) | xcd;
  int bb = bh >> 4, hh = bh & 15;
  int tid = threadIdx.x, w = tid >> 6, l = tid & 63;
  int r = l & 15, qd = l >> 4;

  const int chunk0 = bx, chunk1 = 31 - bx;
  int nmax = 32 - bx;              // chunk1 active every iter; chunk0 for kt <= bx
  int qloc = w * 16 + r;           // within-chunk q row owned by lane r

  // Q b-fragments (q pre-scaled by 1/8*log2e at GEMM0 epilogue)
  s16x8 qf[2][2];
#pragma unroll
  for (int c = 0; c < 2; ++c) {
    int qbase = (c ? chunk1 : chunk0) * 64 + w * 16;
#pragma unroll
    for (int s = 0; s < 2; ++s)
      qf[c][s] = *(const s16x8*)(qg + ((size_t)bh * 2048 + qbase + r) * 64 + s * 32 + qd * 8);
  }

  s16x8 onesf;
#pragma unroll
  for (int e = 0; e < 8; ++e) onesf[e] = (short)0x3F80;  // bf16 1.0

  f32x4 o[2][4] = {};    // O^T: o[c][j][g] = O[q=qbase_c + r][d = 16j + 4qd + g]
  f32x4 lacc[2] = {};    // ones-MFMA row-sum

  // staging lane geometry
  int rl = l >> 3;
  int cg = (l & 7) ^ rl;
  const u16* kbase = kg + (size_t)bh * 2048 * 64;
  const u16* vbase = vtg + (size_t)bh * 64 * 2048;

  auto stage = [&](int kt, int buf) {
    int kk0 = kt * 64;
#pragma unroll
    for (int p = 0; p < 2; ++p) {
      int row = p * 32 + w * 8 + rl;
      gll16(kbase + ((size_t)(kk0 + row)) * 64 + cg * 8, Ks[buf] + p * 2048 + w * 512);
      gll16(vbase + (size_t)row * 2048 + kk0 + cg * 8, Vs[buf] + p * 2048 + w * 512);
    }
  };

  // softmax on one chunk's S^T fragments -> PV B-operand fragments, in-register.
  // sacc[j][g] = S[q=r][k=16j+4qd+g]; output pa[s][e] = P[q=r][k=32s+8qd+e].
  // Exchange among lanes {r,r+16,r+32,r+48}: permlane32_swap then permlane16_swap
  // on bf16-pair words (j,j+1) yields u_s[p], u_s[2+p] directly.
  auto smax = [&](f32x4 (&sc)[4], s16x8 (&pac)[2], bool mask) {
    unsigned pk[4][2];
#pragma unroll
    for (int j = 0; j < 4; ++j) {
      float p0, p1, p2, p3;  // k-local = 16j + 4qd + g
      if (mask) {
        int kb0 = 16 * j + 4 * qd;
        p0 = (kb0 + 0 > qloc) ? 0.f : __builtin_amdgcn_exp2f(sc[j][0]);
        p1 = (kb0 + 1 > qloc) ? 0.f : __builtin_amdgcn_exp2f(sc[j][1]);
        p2 = (kb0 + 2 > qloc) ? 0.f : __builtin_amdgcn_exp2f(sc[j][2]);
        p3 = (kb0 + 3 > qloc) ? 0.f : __builtin_amdgcn_exp2f(sc[j][3]);
      } else {
        p0 = __builtin_amdgcn_exp2f(sc[j][0]);
        p1 = __builtin_amdgcn_exp2f(sc[j][1]);
        p2 = __builtin_amdgcn_exp2f(sc[j][2]);
        p3 = __builtin_amdgcn_exp2f(sc[j][3]);
      }
      pk[j][0] = pk_trunc(p1, p0);
      pk[j][1] = pk_trunc(p3, p2);
    }
#pragma unroll
    for (int s = 0; s < 2; ++s) {
      unsigned a0 = pk[2 * s][0], b0 = pk[2 * s + 1][0];
      asm("v_permlane32_swap_b32 %0, %1" : "+v"(a0), "+v"(b0));
      asm("v_permlane16_swap_b32 %0, %1" : "+v"(a0), "+v"(b0));
      unsigned a1 = pk[2 * s][1], b1 = pk[2 * s + 1][1];
      asm("v_permlane32_swap_b32 %0, %1" : "+v"(a1), "+v"(b1));
      asm("v_permlane16_swap_b32 %0, %1" : "+v"(a1), "+v"(b1));
      pac[s] = mk_pa(a0, a1, b0, b1);
    }
  };

  stage(0, 0);
  __syncthreads();  // buf0 visible

  for (int kt = 0; kt < nmax; ++kt) {
    int cur = kt & 1;
    if (kt + 1 < nmax) stage(kt + 1, cur ^ 1);  // prefetch flies under compute
    bool act0 = (kt <= bx);

    // ---- QK^T: kf read once, feeds both chunks ----
    f32x4 s0[4], s1[4];
#pragma unroll
    for (int j = 0; j < 4; ++j) {
      s1[j] = f32x4{0.f, 0.f, 0.f, 0.f};
      if (act0) s0[j] = f32x4{0.f, 0.f, 0.f, 0.f};
    }
    __builtin_amdgcn_s_setprio(1);
#pragma unroll
    for (int s = 0; s < 2; ++s) {
#pragma unroll
      for (int j = 0; j < 4; ++j) {
        s16x8 kf = *(const s16x8*)(Ks[cur] + (16 * j + r) * 64 + ((s * 4 + qd) ^ (r & 7)) * 8);
        s1[j] = mfma16(kf, qf[1][s], s1[j]);
        if (act0) s0[j] = mfma16(kf, qf[0][s], s0[j]);
      }
    }
    __builtin_amdgcn_s_setprio(0);

    // ---- softmax + in-register P redistribution ----
    s16x8 pa0[2], pa1[2];
    smax(s1, pa1, kt == chunk1);
    lacc[1] = mfma16(onesf, pa1[0], lacc[1]);
    lacc[1] = mfma16(onesf, pa1[1], lacc[1]);
    if (act0) {
      smax(s0, pa0, kt == chunk0);
      lacc[0] = mfma16(onesf, pa0[0], lacc[0]);
      lacc[0] = mfma16(onesf, pa0[1], lacc[0]);
    }

    // ---- PV: vf read once, feeds both chunks ----
    __builtin_amdgcn_s_setprio(1);
#pragma unroll
    for (int s = 0; s < 2; ++s) {
#pragma unroll
      for (int j = 0; j < 4; ++j) {
        s16x8 vf = *(const s16x8*)(Vs[cur] + (16 * j + r) * 64 + ((s * 4 + qd) ^ (r & 7)) * 8);
        o[1][j] = mfma16(vf, pa1[s], o[1][j]);
        if (act0) o[0][j] = mfma16(vf, pa0[s], o[0][j]);
      }
    }
    __builtin_amdgcn_s_setprio(0);

    __syncthreads();  // reads of buf[cur] done + prefetch into buf[cur^1] landed
  }

  // epilogue: lane (r,qd), chunk c: y[q = qbase_c + r][d = 16j + 4qd + g], packed x4
#pragma unroll
  for (int c = 0; c < 2; ++c) {
    int qbase = (c ? chunk1 : chunk0) * 64 + w * 16;
    float inv = 1.0f / lacc[c][0];
    size_t rowoff = ((size_t)bb * 2048 + qbase + r) * 1024 + hh * 64;
#pragma unroll
    for (int j = 0; j < 4; ++j) {
      u16x4 yv;
      yv[0] = f2bf(o[c][j][0] * inv);
      yv[1] = f2bf(o[c][j][1] * inv);
      yv[2] = f2bf(o[c][j][2] * inv);
      yv[3] = f2bf(o[c][j][3] * inv);
      *(u16x4*)(yg + rowoff + 16 * j + 4 * qd) = yv;
    }
  }
}

// ---------------- launch ----------------
extern "C" void kernel_launch(void* const* d_in, const int* in_sizes, int n_in,
                              void* d_out, int out_size, void* d_ws, size_t ws_size,
                              hipStream_t stream) {
  const float* x      = (const float*)d_in[0];
  const float* w_attn = (const float*)d_in[1];
  const float* b_attn = (const float*)d_in[2];
  const float* w_proj = (const float*)d_in[3];
  const float* b_proj = (const float*)d_in[4];
  float* out = (float*)d_out;

  char* ws = (char*)d_ws;
  size_t off = 0;
  auto alloc = [&](size_t bytes) -> void* {
    void* p = ws + off;
    off += (bytes + 255) & ~(size_t)255;
    return p;
  };
  const size_t BT = 8192, C = 1024;
  u16* xb  = (u16*)alloc(BT * C * 2);          // x bf16; reused as y
  u16* waT = (u16*)alloc(3072 * 1024 * 2);
  u16* wpT = (u16*)alloc(1024 * 1024 * 2);
  u16* qb  = (u16*)alloc(BT * C * 2);          // [BH][T][D], q pre-scaled
  u16* kb  = (u16*)alloc(BT * C * 2);          // [BH][T][D]
  u16* vtb = (u16*)alloc(BT * C * 2);          // [BH][D][T] (written by GEMM0 directly)
  (void)ws_size; (void)in_sizes; (void)n_in; (void)out_size;

  k_convert_x<<<4096, 256, 0, stream>>>(x, xb);
  k_transpose_w<<<dim3(96, 32), 256, 0, stream>>>(w_attn, waT, 1024, 3072);
  k_transpose_w<<<dim3(32, 32), 256, 0, stream>>>(w_proj, wpT, 1024, 1024);
  k_gemm<0><<<1536, 256, 0, stream>>>(xb, waT, b_attn, nullptr, qb, kb, vtb, 1024, 32);
  k_attn<<<1024, 256, 0, stream>>>(qb, kb, vtb, xb /* y reuses xb */);
  k_gemm<1><<<512, 256, 0, stream>>>(xb, wpT, b_proj, out, nullptr, nullptr, nullptr, 1024, 32);
}